// Round 3
// baseline (677.606 us; speedup 1.0000x reference)
//
#include <hip/hip_runtime.h>
#include <hip/hip_fp16.h>
#include <math.h>

#define NXY 320
#define NC 20
#define NT 25
#define NPIX 102400   // 320*320
#define PI_F 3.14159265358979f
#define TWOPI_F 6.28318530717959f

__device__ __forceinline__ float2 cmul(float2 a, float2 b) {
    return make_float2(a.x * b.x - a.y * b.y, a.x * b.y + a.y * b.x);
}

// gfx950 VALU-pipe lane swaps for the h=32 / h=16 butterfly stages.
#if defined(__has_builtin)
#if __has_builtin(__builtin_amdgcn_permlane32_swap) && __has_builtin(__builtin_amdgcn_permlane16_swap)
#define USE_PERMLANE_SWAP 1
#endif
#endif
#ifndef USE_PERMLANE_SWAP
#define USE_PERMLANE_SWAP 0
#endif

typedef unsigned uint2e __attribute__((ext_vector_type(2)));

// Per-lane FFT twiddles — invariant across every FFT a thread performs.
struct Tw {
    float2 st[6];   // stage twiddle: (1,0) lower half, e^{+i*pi*i/h} upper
    float  sgn[6];  // +1 lower, -1 upper
    float2 w5[5];   // w5[r] = e^{+2*pi*i * r*J / 320}
    int J;          // bitrev6(lane)
};

__device__ __forceinline__ void tw_init(Tw& t) {
    const int lane = threadIdx.x & 63;
    #pragma unroll
    for (int s = 0; s < 6; ++s) {
        const int h = 32 >> s;
        const bool up = (lane & h) != 0;
        t.sgn[s] = up ? -1.0f : 1.0f;
        if (up) {
            float ss, cc;
            __sincosf(PI_F * (float)(lane & (h - 1)) / (float)h, &ss, &cc);
            t.st[s] = make_float2(cc, ss);
        } else {
            t.st[s] = make_float2(1.0f, 0.0f);
        }
    }
    t.J = (int)(__brev((unsigned)lane) >> 26);
    t.w5[0] = make_float2(1.0f, 0.0f);
    #pragma unroll
    for (int r = 1; r < 5; ++r) {
        float ss, cc;
        __sincosf(TWOPI_F * (float)(r * t.J) / 320.0f, &ss, &cc);
        t.w5[r] = make_float2(cc, ss);
    }
}

// K interleaved 320-point DFTs (+i sign) by one wave. IN-PLACE: result in x.
// Stages h=32,16 use permlane*_swap (VALU pipe, ~3 cyc) instead of
// ds_swizzle (DS pipe, ~30 cyc latency) — removes 1/3 of DS traffic and
// 2 of 6 links in the dependent shuffle chain.
template <int K>
__device__ __forceinline__ void fft320xK(const Tw& t, float2 (&x)[K][5]) {
#if USE_PERMLANE_SWAP
    #pragma unroll
    for (int s = 0; s < 2; ++s) {
        #pragma unroll
        for (int r = 0; r < 5; ++r) {
            #pragma unroll
            for (int k = 0; k < K; ++k) {
                uint2e px, py;
                if (s == 0) {
                    px = __builtin_amdgcn_permlane32_swap(
                        __float_as_uint(x[k][r].x), __float_as_uint(x[k][r].x), false, false);
                    py = __builtin_amdgcn_permlane32_swap(
                        __float_as_uint(x[k][r].y), __float_as_uint(x[k][r].y), false, false);
                } else {
                    px = __builtin_amdgcn_permlane16_swap(
                        __float_as_uint(x[k][r].x), __float_as_uint(x[k][r].x), false, false);
                    py = __builtin_amdgcn_permlane16_swap(
                        __float_as_uint(x[k][r].y), __float_as_uint(x[k][r].y), false, false);
                }
                // px[0]=value at (lane & ~h) [lo], px[1]=value at (lane | h) [hi]
                float dx = fmaf(t.sgn[s], __uint_as_float(px[1]), __uint_as_float(px[0]));
                float dy = fmaf(t.sgn[s], __uint_as_float(py[1]), __uint_as_float(py[0]));
                x[k][r].x = dx * t.st[s].x - dy * t.st[s].y;
                x[k][r].y = dx * t.st[s].y + dy * t.st[s].x;
            }
        }
    }
    constexpr int S0 = 2;
#else
    constexpr int S0 = 0;
#endif
    #pragma unroll
    for (int s = S0; s < 6; ++s) {
        const int h = 32 >> s;
        #pragma unroll
        for (int r = 0; r < 5; ++r) {
            #pragma unroll
            for (int k = 0; k < K; ++k) {
                float ox = __shfl_xor(x[k][r].x, h);
                float oy = __shfl_xor(x[k][r].y, h);
                float dx = fmaf(t.sgn[s], x[k][r].x, ox);
                float dy = fmaf(t.sgn[s], x[k][r].y, oy);
                x[k][r].x = dx * t.st[s].x - dy * t.st[s].y;
                x[k][r].y = dx * t.st[s].y + dy * t.st[s].x;
            }
        }
    }
    const float W5x[5] = {1.0f, 0.309016994f, -0.809016994f, -0.809016994f, 0.309016994f};
    const float W5y[5] = {0.0f, 0.951056516f, 0.587785252f, -0.587785252f, -0.951056516f};
    #pragma unroll
    for (int k = 0; k < K; ++k) {
        float2 T[5];
        T[0] = x[k][0];
        #pragma unroll
        for (int r = 1; r < 5; ++r) T[r] = cmul(x[k][r], t.w5[r]);
        #pragma unroll
        for (int s5 = 0; s5 < 5; ++s5) {
            float2 acc = T[0];
            #pragma unroll
            for (int r = 1; r < 5; ++r) {
                const int kk = (r * s5) % 5;
                acc.x += T[r].x * W5x[kk] - T[r].y * W5y[kk];
                acc.y += T[r].x * W5y[kk] + T[r].y * W5x[kk];
            }
            x[k][s5] = acc;
        }
    }
}

// smapsC[c][p] = conj(smaps[p][c]) * (-1)^(m+n) / 320   (fp32 staging table)
__global__ __launch_bounds__(256) void k_prep_smaps(const float* __restrict__ smr,
                                                    const float* __restrict__ smi,
                                                    float2* __restrict__ smapsC) {
    const int p0 = blockIdx.x * 64;
    __shared__ float s_r[64 * 21];
    __shared__ float s_i[64 * 21];
    for (int j = threadIdx.x; j < 64 * NC; j += blockDim.x) {
        int p = j / NC, c = j - p * NC;
        s_r[p * 21 + c] = smr[(size_t)p0 * NC + j];
        s_i[p * 21 + c] = smi[(size_t)p0 * NC + j];
    }
    __syncthreads();
    for (int j = threadIdx.x; j < 64 * NC; j += blockDim.x) {
        int c = j >> 6, p = j & 63;
        int pg = p0 + p;
        int m = pg / NXY, n = pg - m * NXY;
        float sgn = (((m + n) & 1) ? -1.0f : 1.0f) * (1.0f / 320.0f);
        smapsC[(size_t)c * NPIX + pg] = make_float2(s_r[p * 21 + c] * sgn,
                                                    -s_i[p * 21 + c] * sgn);
    }
}

// smapsP[((c*320 + v)*5 + s5)*64 + lane] = smapsC[c][(bitrev6(lane)+64*s5)*320 + v] (half2)
__global__ __launch_bounds__(256) void k_perm_smaps(const float2* __restrict__ smapsC,
                                                    __half2* __restrict__ smapsP) {
    const int c = blockIdx.x;
    const int s5 = blockIdx.y;
    const int v0 = blockIdx.z * 64;
    __shared__ __half2 t2[64 * 65];
    for (int j = threadIdx.x; j < 64 * 64; j += blockDim.x) {
        int ur = j >> 6, vc = j & 63;
        float2 v = smapsC[(size_t)c * NPIX + (size_t)(s5 * 64 + ur) * NXY + v0 + vc];
        t2[ur * 65 + vc] = __floats2half2_rn(v.x, v.y);
    }
    __syncthreads();
    for (int j = threadIdx.x; j < 64 * 64; j += blockDim.x) {
        int vr = j >> 6, lane = j & 63;
        int J = (int)(__brev((unsigned)lane) >> 26);
        smapsP[(size_t)((c * NXY + v0 + vr) * 5 + s5) * 64 + lane] = t2[J * 65 + vr];
    }
}

// ksS[c][p] = (ksr + i*ksi)(p,c) * (-1)^(m+n)   (half2, pre-mask)
__global__ __launch_bounds__(256) void k_prep_ks(const float* __restrict__ ksr,
                                                 const float* __restrict__ ksi,
                                                 __half2* __restrict__ ksS) {
    const int p0 = blockIdx.x * 64;
    __shared__ float s_r[64 * 21];
    __shared__ float s_i[64 * 21];
    for (int j = threadIdx.x; j < 64 * NC; j += blockDim.x) {
        int p = j / NC, c = j - p * NC;
        s_r[p * 21 + c] = ksr[(size_t)p0 * NC + j];
        s_i[p * 21 + c] = ksi[(size_t)p0 * NC + j];
    }
    __syncthreads();
    for (int j = threadIdx.x; j < 64 * NC; j += blockDim.x) {
        int c = j >> 6, p = j & 63;
        int pg = p0 + p;
        int m = pg / NXY, n = pg - m * NXY;
        float sgn = ((m + n) & 1) ? -1.0f : 1.0f;
        ksS[(size_t)c * NPIX + pg] =
            __floats2half2_rn(s_r[p * 21 + c] * sgn, s_i[p * 21 + c] * sgn);
    }
}

// Dense transpose: maskT[(c*G+tc)][p] = (half)mask[p][c*25 + t0 + tc].
__global__ __launch_bounds__(256) void k_transpose_mask(const float* __restrict__ mask,
                                                        __half* __restrict__ maskT,
                                                        int t0, int G) {
    const int p0 = blockIdx.x * 64;
    const int c = blockIdx.y;
    __shared__ float tile[64 * 26];
    if (G == NT) {
        for (int j = threadIdx.x; j < 64 * NT; j += 256) {
            int pl = j / NT, tc = j - pl * NT;  // compile-time divisor
            tile[pl * 26 + tc] = mask[(size_t)(p0 + pl) * (NC * NT) + c * NT + tc];
        }
    } else {
        for (int j = threadIdx.x; j < 64 * G; j += 256) {
            int pl = j / G, tc = j - pl * G;
            tile[pl * 26 + tc] = mask[(size_t)(p0 + pl) * (NC * NT) + c * NT + t0 + tc];
        }
    }
    __syncthreads();
    for (int j = threadIdx.x; j < 16 * G; j += 256) {
        int p4 = (j & 15) * 4, tc = j >> 4;
        union { __half2 h2[2]; uint2 u; } pk;
        pk.h2[0] = __floats2half2_rn(tile[(p4 + 0) * 26 + tc], tile[(p4 + 1) * 26 + tc]);
        pk.h2[1] = __floats2half2_rn(tile[(p4 + 2) * 26 + tc], tile[(p4 + 3) * 26 + tc]);
        *reinterpret_cast<uint2*>(maskT + (size_t)(c * G + tc) * NPIX + p0 + p4) = pk.u;
    }
}

// FUSED: maskT*kspace + row FFTs (over n). One block = 16 rows of one (c,tc).
// Raw loads issued BEFORE tw_init so sincos overlaps global latency.
__global__ __launch_bounds__(256) void k_fft_rows(const __half* __restrict__ maskT,
                                                  const __half2* __restrict__ ksS,
                                                  __half2* __restrict__ Z,
                                                  int G) {
    const int q = blockIdx.x;       // c*G + tc
    const int mtile = blockIdx.y;   // 0..19
    const int c = q / G;            // once per block (scalar)
    const int wave = threadIdx.x >> 6;
    const int lane = threadIdx.x & 63;
    const int m0 = mtile * 16;
    __shared__ __half2 tile[NXY * 17];  // [v][16 + 1 pad]
    const __half2* ks_c = ksS + (size_t)c * NPIX;
    const __half* mk_q = maskT + (size_t)q * NPIX;
    __half2 kraw[4][5];
    __half  mraw[4][5];
    #pragma unroll
    for (int k = 0; k < 4; ++k) {
        const int pbase = (m0 + wave + 4 * k) * NXY + lane * 5;
        const __half2* kp = ks_c + pbase;
        const __half* mp = mk_q + pbase;
        #pragma unroll
        for (int r = 0; r < 5; ++r) { kraw[k][r] = kp[r]; mraw[k][r] = mp[r]; }
    }
    Tw t;
    tw_init(t);   // TRANS-pipe work overlaps the loads above
    float2 x[4][5];
    #pragma unroll
    for (int k = 0; k < 4; ++k) {
        #pragma unroll
        for (int r = 0; r < 5; ++r) {
            float2 kv = __half22float2(kraw[k][r]);
            float mkv = __half2float(mraw[k][r]);
            x[k][r] = make_float2(kv.x * mkv, kv.y * mkv);
        }
    }
    fft320xK<4>(t, x);
    #pragma unroll
    for (int k = 0; k < 4; ++k) {
        const int mm = wave + 4 * k;
        #pragma unroll
        for (int s5 = 0; s5 < 5; ++s5) {
            int v = t.J + 64 * s5;
            tile[v * 17 + mm] = __floats2half2_rn(x[k][s5].x, x[k][s5].y);
        }
    }
    __syncthreads();
    __half2* dst = Z + (size_t)q * NPIX + m0;
    for (int j = threadIdx.x; j < NXY * 16; j += blockDim.x) {
        int mm = j & 15, v = j >> 4;
        dst[(size_t)v * NXY + mm] = tile[v * 17 + mm];
    }
}

// Column FFTs (over m) + coil combine; K=2 ILP, coils split across blockIdx.z.
// Software-pipelined coil loop: Z for coil c+1 prefetches under coil c's FFT;
// smaps for c+1 prefetch under iteration c+1's convert+FFT.
__global__ __launch_bounds__(256) void k_fft_cols_combine(const __half2* __restrict__ Z,
                                                          const __half2* __restrict__ smapsP,
                                                          __half2* __restrict__ imtP,
                                                          int t0, int G) {
    const int vtile = blockIdx.x;   // 0..39
    const int tc = blockIdx.y;
    const int half = blockIdx.z;    // 0/1 -> coils [10h, 10h+10)
    const int wave = threadIdx.x >> 6;
    const int lane = threadIdx.x & 63;
    const int v0 = vtile * 8;
    const int vA = v0 + wave;       // vB = vA + 4 (constant offset from colA/spA)
    __shared__ __half2 tile[NXY * 9];   // [u][8 v + 1 pad]
    const int c0 = half * 10;
    const size_t zStride = (size_t)G * NPIX;          // half2 per coil in Z
    const size_t sStride = (size_t)NXY * 5 * 64;      // half2 per coil in smapsP
    const __half2* colA = Z + (size_t)(c0 * G + tc) * NPIX + (size_t)vA * NXY + lane * 5;
    const __half2* spA = smapsP + (size_t)((c0 * NXY + vA) * 5) * 64 + lane;

    // Prologue prefetch (coil c0): Z columns + smaps, raw half2 registers.
    __half2 pf[2][5], sm[2][5];
    #pragma unroll
    for (int r = 0; r < 5; ++r) {
        pf[0][r] = colA[r];
        pf[1][r] = colA[4 * NXY + r];
    }
    #pragma unroll
    for (int s5 = 0; s5 < 5; ++s5) {
        sm[0][s5] = spA[s5 * 64];
        sm[1][s5] = spA[s5 * 64 + 4 * 5 * 64];
    }
    Tw t;
    tw_init(t);   // overlaps prologue loads
    float2 acc[2][5];
    #pragma unroll
    for (int k = 0; k < 2; ++k)
        #pragma unroll
        for (int s5 = 0; s5 < 5; ++s5) acc[k][s5] = make_float2(0.f, 0.f);

    for (int ci = 0; ci < 10; ++ci) {
        // consume prefetched Z
        float2 x[2][5];
        #pragma unroll
        for (int r = 0; r < 5; ++r) {
            x[0][r] = __half22float2(pf[0][r]);
            x[1][r] = __half22float2(pf[1][r]);
        }
        // issue next coil's Z loads — hidden under the FFT below
        if (ci < 9) {
            colA += zStride;
            #pragma unroll
            for (int r = 0; r < 5; ++r) {
                pf[0][r] = colA[r];
                pf[1][r] = colA[4 * NXY + r];
            }
        }
        fft320xK<2>(t, x);
        // combine with (prefetched) smaps for this coil
        #pragma unroll
        for (int s5 = 0; s5 < 5; ++s5) {
            float2 smA = __half22float2(sm[0][s5]);
            float2 smB = __half22float2(sm[1][s5]);
            float2 ta = cmul(x[0][s5], smA);
            float2 tb = cmul(x[1][s5], smB);
            acc[0][s5].x += ta.x; acc[0][s5].y += ta.y;
            acc[1][s5].x += tb.x; acc[1][s5].y += tb.y;
        }
        // issue next coil's smaps loads — hidden under next iter's convert+FFT
        if (ci < 9) {
            spA += sStride;
            #pragma unroll
            for (int s5 = 0; s5 < 5; ++s5) {
                sm[0][s5] = spA[s5 * 64];
                sm[1][s5] = spA[s5 * 64 + 4 * 5 * 64];
            }
        }
    }
    #pragma unroll
    for (int s5 = 0; s5 < 5; ++s5) {
        int u = t.J + 64 * s5;
        tile[u * 9 + wave] = __floats2half2_rn(acc[0][s5].x, acc[0][s5].y);
        tile[u * 9 + 4 + wave] = __floats2half2_rn(acc[1][s5].x, acc[1][s5].y);
    }
    __syncthreads();
    __half2* dst = imtP + (size_t)(half * NT + t0 + tc) * NPIX + v0;
    for (int j = threadIdx.x; j < NXY * 8; j += blockDim.x) {
        int vv = j & 7, u = j >> 3;
        dst[(size_t)u * NXY + vv] = tile[u * 9 + vv];
    }
}

// Bilinear warp + sum over t; reduces the two coil-half partials.
__global__ __launch_bounds__(256) void k_warp_sum(const __half2* __restrict__ imtP,
                                                  const float* __restrict__ flow,
                                                  float* __restrict__ out) {
    const int p0 = blockIdx.x * 256;
    const int tid = threadIdx.x;
    __shared__ float s_fl[2 * NT * 257];
    for (int j = tid; j < 256 * 50; j += 256) {
        int pp = j / 50, rem = j - pp * 50;
        int d = rem / 25, tt = rem - d * 25;
        s_fl[(d * NT + tt) * 257 + pp] = flow[(size_t)p0 * 50 + j];
    }
    __syncthreads();
    const int p = p0 + tid;
    const int x = p / NXY, y = p - x * NXY;
    const float fx = (float)x, fy = (float)y;
    float ar = 0.f, ai = 0.f;
    for (int t = 0; t < NT; ++t) {
        float u = s_fl[t * 257 + tid];
        float v = s_fl[(NT + t) * 257 + tid];
        float xs = fminf(fmaxf(fx + u, 0.0f), 319.0f);
        float ys = fminf(fmaxf(fy + v, 0.0f), 319.0f);
        float x0f = floorf(xs), y0f = floorf(ys);
        int x0 = (int)x0f, y0 = (int)y0f;
        int x1 = min(x0 + 1, NXY - 1), y1 = min(y0 + 1, NXY - 1);
        float wx = xs - x0f, wy = ys - y0f;
        const __half2* b0 = imtP + (size_t)t * NPIX;
        const __half2* b1 = imtP + (size_t)(NT + t) * NPIX;
        int i00 = x0 * NXY + y0, i01 = x0 * NXY + y1;
        int i10 = x1 * NXY + y0, i11 = x1 * NXY + y1;
        float2 c00 = __half22float2(b0[i00]); float2 d00 = __half22float2(b1[i00]);
        float2 c01 = __half22float2(b0[i01]); float2 d01 = __half22float2(b1[i01]);
        float2 c10 = __half22float2(b0[i10]); float2 d10 = __half22float2(b1[i10]);
        float2 c11 = __half22float2(b0[i11]); float2 d11 = __half22float2(b1[i11]);
        c00.x += d00.x; c00.y += d00.y;
        c01.x += d01.x; c01.y += d01.y;
        c10.x += d10.x; c10.y += d10.y;
        c11.x += d11.x; c11.y += d11.y;
        float w00 = (1.f - wx) * (1.f - wy), w01 = (1.f - wx) * wy;
        float w10 = wx * (1.f - wy), w11 = wx * wy;
        ar += c00.x * w00 + c01.x * w01 + c10.x * w10 + c11.x * w11;
        ai += c00.y * w00 + c01.y * w01 + c10.y * w10 + c11.y * w11;
    }
    out[p] = ar;
    out[NPIX + p] = ai;
}

extern "C" void kernel_launch(void* const* d_in, const int* in_sizes, int n_in,
                              void* d_out, int out_size, void* d_ws, size_t ws_size,
                              hipStream_t stream) {
    const float* ksr = (const float*)d_in[0];
    const float* ksi = (const float*)d_in[1];
    const float* mask = (const float*)d_in[2];
    const float* smr = (const float*)d_in[3];
    const float* smi = (const float*)d_in[4];
    const float* flow = (const float*)d_in[5];
    float* out = (float*)d_out;

    char* ws = (char*)d_ws;
    const size_t smapsC_bytes = (size_t)NC * NPIX * sizeof(float2);          // 16.4 MB
    const size_t smapsP_bytes = (size_t)NC * NPIX * sizeof(__half2);         // 8.2 MB
    const size_t ksS_bytes = (size_t)NC * NPIX * sizeof(__half2);            // 8.2 MB
    const size_t imtP_bytes = (size_t)2 * NT * NPIX * sizeof(__half2);       // 20.5 MB
    const size_t fixed = smapsC_bytes + smapsP_bytes + ksS_bytes + imtP_bytes;
    // per-t: Z (half2) + maskT (half)
    const size_t per_t = (size_t)NC * NPIX * (sizeof(__half2) + sizeof(__half)); // 12.3 MB

    int G = 1;
    if (ws_size > fixed + per_t) {
        size_t g = (ws_size - fixed) / per_t;
        G = (int)(g > (size_t)NT ? (size_t)NT : g);
    }
    if (G < 1) G = 1;

    float2* smapsC = (float2*)ws;
    __half2* smapsP = (__half2*)(ws + smapsC_bytes);
    __half2* ksS = (__half2*)(ws + smapsC_bytes + smapsP_bytes);
    __half2* imtP = (__half2*)(ws + smapsC_bytes + smapsP_bytes + ksS_bytes);
    __half2* Z = (__half2*)(ws + fixed);
    __half* maskT = (__half*)(ws + fixed + (size_t)NC * G * NPIX * sizeof(__half2));

    k_prep_smaps<<<NPIX / 64, 256, 0, stream>>>(smr, smi, smapsC);
    k_perm_smaps<<<dim3(NC, 5, 5), 256, 0, stream>>>(smapsC, smapsP);
    k_prep_ks<<<NPIX / 64, 256, 0, stream>>>(ksr, ksi, ksS);
    for (int t0 = 0; t0 < NT; t0 += G) {
        int g = (NT - t0) < G ? (NT - t0) : G;
        k_transpose_mask<<<dim3(NPIX / 64, NC), 256, 0, stream>>>(mask, maskT, t0, g);
        k_fft_rows<<<dim3(NC * g, 20), 256, 0, stream>>>(maskT, ksS, Z, g);
        k_fft_cols_combine<<<dim3(40, g, 2), 256, 0, stream>>>(Z, smapsP, imtP, t0, g);
    }
    k_warp_sum<<<NPIX / 256, 256, 0, stream>>>(imtP, flow, out);
}

// Round 4
// 664.599 us; speedup vs baseline: 1.0196x; 1.0196x over previous
//
#include <hip/hip_runtime.h>
#include <hip/hip_fp16.h>
#include <math.h>

#define NXY 320
#define NC 20
#define NT 25
#define NPIX 102400   // 320*320
#define PI_F 3.14159265358979f
#define TWOPI_F 6.28318530717959f

// Packed 2xf32 — lowers to v_pk_fma_f32 / v_pk_mul_f32 / v_pk_add_f32 on gfx950.
typedef float f2 __attribute__((ext_vector_type(2)));
typedef unsigned uint2e __attribute__((ext_vector_type(2)));

__device__ __forceinline__ f2 mkf2(float a, float b) { f2 r; r.x = a; r.y = b; return r; }

// gfx950 VALU-pipe lane swaps for the h=32 / h=16 butterfly stages.
#if defined(__has_builtin)
#if __has_builtin(__builtin_amdgcn_permlane32_swap) && __has_builtin(__builtin_amdgcn_permlane16_swap)
#define USE_PERMLANE_SWAP 1
#endif
#endif
#ifndef USE_PERMLANE_SWAP
#define USE_PERMLANE_SWAP 0
#endif

// Per-lane FFT twiddles, pre-packed for pk-f32 complex multiply:
//   res = d * stxx + d.yx * stym   computes (d.x*c - d.y*s, d.x*s + d.y*c)
struct Tw {
    f2 stxx[6];   // (c, c)
    f2 stym[6];   // (-s, s)
    float sgn[6]; // +1 lower, -1 upper
    f2 w5xx[5];   // (c, c) of e^{+2*pi*i * r*J / 320}
    f2 w5ym[5];   // (-s, s)
    int J;        // bitrev6(lane)
};

__device__ __forceinline__ void tw_init(Tw& t) {
    const int lane = threadIdx.x & 63;
    #pragma unroll
    for (int s = 0; s < 6; ++s) {
        const int h = 32 >> s;
        const bool up = (lane & h) != 0;
        t.sgn[s] = up ? -1.0f : 1.0f;
        float cc = 1.0f, ss = 0.0f;
        if (up) __sincosf(PI_F * (float)(lane & (h - 1)) / (float)h, &ss, &cc);
        t.stxx[s] = mkf2(cc, cc);
        t.stym[s] = mkf2(-ss, ss);
    }
    t.J = (int)(__brev((unsigned)lane) >> 26);
    t.w5xx[0] = mkf2(1.0f, 1.0f);
    t.w5ym[0] = mkf2(0.0f, 0.0f);
    #pragma unroll
    for (int r = 1; r < 5; ++r) {
        float ss, cc;
        __sincosf(TWOPI_F * (float)(r * t.J) / 320.0f, &ss, &cc);
        t.w5xx[r] = mkf2(cc, cc);
        t.w5ym[r] = mkf2(-ss, ss);
    }
}

// K interleaved 320-point DFTs (+i sign) by one wave. IN-PLACE: result in x.
// All complex arithmetic on f2 vectors -> packed v_pk_* f32 ops (2x issue width).
template <int K>
__device__ __forceinline__ void fft320xK(const Tw& t, f2 (&x)[K][5]) {
#if USE_PERMLANE_SWAP
    #pragma unroll
    for (int s = 0; s < 2; ++s) {
        #pragma unroll
        for (int r = 0; r < 5; ++r) {
            #pragma unroll
            for (int k = 0; k < K; ++k) {
                uint2e px, py;
                if (s == 0) {
                    px = __builtin_amdgcn_permlane32_swap(
                        __float_as_uint(x[k][r].x), __float_as_uint(x[k][r].x), false, false);
                    py = __builtin_amdgcn_permlane32_swap(
                        __float_as_uint(x[k][r].y), __float_as_uint(x[k][r].y), false, false);
                } else {
                    px = __builtin_amdgcn_permlane16_swap(
                        __float_as_uint(x[k][r].x), __float_as_uint(x[k][r].x), false, false);
                    py = __builtin_amdgcn_permlane16_swap(
                        __float_as_uint(x[k][r].y), __float_as_uint(x[k][r].y), false, false);
                }
                // px[0] = value at (lane & ~h) [lo], px[1] = value at (lane | h) [hi]
                f2 lo = mkf2(__uint_as_float(px[0]), __uint_as_float(py[0]));
                f2 hi = mkf2(__uint_as_float(px[1]), __uint_as_float(py[1]));
                f2 d = lo + hi * t.sgn[s];
                x[k][r] = d * t.stxx[s] + d.yx * t.stym[s];
            }
        }
    }
    constexpr int S0 = 2;
#else
    constexpr int S0 = 0;
#endif
    #pragma unroll
    for (int s = S0; s < 6; ++s) {
        const int h = 32 >> s;
        #pragma unroll
        for (int r = 0; r < 5; ++r) {
            #pragma unroll
            for (int k = 0; k < K; ++k) {
                f2 o = mkf2(__shfl_xor(x[k][r].x, h), __shfl_xor(x[k][r].y, h));
                f2 d = o + x[k][r] * t.sgn[s];
                x[k][r] = d * t.stxx[s] + d.yx * t.stym[s];
            }
        }
    }
    const float W5x[5] = {1.0f, 0.309016994f, -0.809016994f, -0.809016994f, 0.309016994f};
    const float W5y[5] = {0.0f, 0.951056516f, 0.587785252f, -0.587785252f, -0.951056516f};
    #pragma unroll
    for (int k = 0; k < K; ++k) {
        f2 T[5];
        T[0] = x[k][0];
        #pragma unroll
        for (int r = 1; r < 5; ++r) {
            f2 a = x[k][r];
            T[r] = a * t.w5xx[r] + a.yx * t.w5ym[r];
        }
        #pragma unroll
        for (int s5 = 0; s5 < 5; ++s5) {
            f2 acc = T[0];
            #pragma unroll
            for (int r = 1; r < 5; ++r) {
                const int kk = (r * s5) % 5;
                acc += T[r] * W5x[kk];
                acc += T[r].yx * mkf2(-W5y[kk], W5y[kk]);
            }
            x[k][s5] = acc;
        }
    }
}

// smapsC[c][p] = conj(smaps[p][c]) * (-1)^(m+n) / 320   (fp32 staging table)
__global__ __launch_bounds__(256) void k_prep_smaps(const float* __restrict__ smr,
                                                    const float* __restrict__ smi,
                                                    float2* __restrict__ smapsC) {
    const int p0 = blockIdx.x * 64;
    __shared__ float s_r[64 * 21];
    __shared__ float s_i[64 * 21];
    for (int j = threadIdx.x; j < 64 * NC; j += blockDim.x) {
        int p = j / NC, c = j - p * NC;
        s_r[p * 21 + c] = smr[(size_t)p0 * NC + j];
        s_i[p * 21 + c] = smi[(size_t)p0 * NC + j];
    }
    __syncthreads();
    for (int j = threadIdx.x; j < 64 * NC; j += blockDim.x) {
        int c = j >> 6, p = j & 63;
        int pg = p0 + p;
        int m = pg / NXY, n = pg - m * NXY;
        float sgn = (((m + n) & 1) ? -1.0f : 1.0f) * (1.0f / 320.0f);
        smapsC[(size_t)c * NPIX + pg] = make_float2(s_r[p * 21 + c] * sgn,
                                                    -s_i[p * 21 + c] * sgn);
    }
}

// smapsP[((c*320 + v)*5 + s5)*64 + lane] = smapsC[c][(bitrev6(lane)+64*s5)*320 + v] (half2)
__global__ __launch_bounds__(256) void k_perm_smaps(const float2* __restrict__ smapsC,
                                                    __half2* __restrict__ smapsP) {
    const int c = blockIdx.x;
    const int s5 = blockIdx.y;
    const int v0 = blockIdx.z * 64;
    __shared__ __half2 t2[64 * 65];
    for (int j = threadIdx.x; j < 64 * 64; j += blockDim.x) {
        int ur = j >> 6, vc = j & 63;
        float2 v = smapsC[(size_t)c * NPIX + (size_t)(s5 * 64 + ur) * NXY + v0 + vc];
        t2[ur * 65 + vc] = __floats2half2_rn(v.x, v.y);
    }
    __syncthreads();
    for (int j = threadIdx.x; j < 64 * 64; j += blockDim.x) {
        int vr = j >> 6, lane = j & 63;
        int J = (int)(__brev((unsigned)lane) >> 26);
        smapsP[(size_t)((c * NXY + v0 + vr) * 5 + s5) * 64 + lane] = t2[J * 65 + vr];
    }
}

// ksS[c][p] = (ksr + i*ksi)(p,c) * (-1)^(m+n)   (half2, pre-mask)
__global__ __launch_bounds__(256) void k_prep_ks(const float* __restrict__ ksr,
                                                 const float* __restrict__ ksi,
                                                 __half2* __restrict__ ksS) {
    const int p0 = blockIdx.x * 64;
    __shared__ float s_r[64 * 21];
    __shared__ float s_i[64 * 21];
    for (int j = threadIdx.x; j < 64 * NC; j += blockDim.x) {
        int p = j / NC, c = j - p * NC;
        s_r[p * 21 + c] = ksr[(size_t)p0 * NC + j];
        s_i[p * 21 + c] = ksi[(size_t)p0 * NC + j];
    }
    __syncthreads();
    for (int j = threadIdx.x; j < 64 * NC; j += blockDim.x) {
        int c = j >> 6, p = j & 63;
        int pg = p0 + p;
        int m = pg / NXY, n = pg - m * NXY;
        float sgn = ((m + n) & 1) ? -1.0f : 1.0f;
        ksS[(size_t)c * NPIX + pg] =
            __floats2half2_rn(s_r[p * 21 + c] * sgn, s_i[p * 21 + c] * sgn);
    }
}

// Dense transpose: maskT[(c*G+tc)][p] = (half)mask[p][c*25 + t0 + tc].
__global__ __launch_bounds__(256) void k_transpose_mask(const float* __restrict__ mask,
                                                        __half* __restrict__ maskT,
                                                        int t0, int G) {
    const int p0 = blockIdx.x * 64;
    const int c = blockIdx.y;
    __shared__ float tile[64 * 26];
    if (G == NT) {
        for (int j = threadIdx.x; j < 64 * NT; j += 256) {
            int pl = j / NT, tc = j - pl * NT;  // compile-time divisor
            tile[pl * 26 + tc] = mask[(size_t)(p0 + pl) * (NC * NT) + c * NT + tc];
        }
    } else {
        for (int j = threadIdx.x; j < 64 * G; j += 256) {
            int pl = j / G, tc = j - pl * G;
            tile[pl * 26 + tc] = mask[(size_t)(p0 + pl) * (NC * NT) + c * NT + t0 + tc];
        }
    }
    __syncthreads();
    for (int j = threadIdx.x; j < 16 * G; j += 256) {
        int p4 = (j & 15) * 4, tc = j >> 4;
        union { __half2 h2[2]; uint2 u; } pk;
        pk.h2[0] = __floats2half2_rn(tile[(p4 + 0) * 26 + tc], tile[(p4 + 1) * 26 + tc]);
        pk.h2[1] = __floats2half2_rn(tile[(p4 + 2) * 26 + tc], tile[(p4 + 3) * 26 + tc]);
        *reinterpret_cast<uint2*>(maskT + (size_t)(c * G + tc) * NPIX + p0 + p4) = pk.u;
    }
}

// FUSED: maskT*kspace + row FFTs (over n). One block = 16 rows of one (c,tc).
// Raw loads issued BEFORE tw_init so sincos overlaps global latency.
__global__ __launch_bounds__(256) void k_fft_rows(const __half* __restrict__ maskT,
                                                  const __half2* __restrict__ ksS,
                                                  __half2* __restrict__ Z,
                                                  int G) {
    const int q = blockIdx.x;       // c*G + tc
    const int mtile = blockIdx.y;   // 0..19
    const int c = q / G;            // once per block (scalar)
    const int wave = threadIdx.x >> 6;
    const int lane = threadIdx.x & 63;
    const int m0 = mtile * 16;
    __shared__ __half2 tile[NXY * 17];  // [v][16 + 1 pad]
    const __half2* ks_c = ksS + (size_t)c * NPIX;
    const __half* mk_q = maskT + (size_t)q * NPIX;
    __half2 kraw[4][5];
    __half  mraw[4][5];
    #pragma unroll
    for (int k = 0; k < 4; ++k) {
        const int pbase = (m0 + wave + 4 * k) * NXY + lane * 5;
        const __half2* kp = ks_c + pbase;
        const __half* mp = mk_q + pbase;
        #pragma unroll
        for (int r = 0; r < 5; ++r) { kraw[k][r] = kp[r]; mraw[k][r] = mp[r]; }
    }
    Tw t;
    tw_init(t);   // TRANS-pipe work overlaps the loads above
    f2 x[4][5];
    #pragma unroll
    for (int k = 0; k < 4; ++k) {
        #pragma unroll
        for (int r = 0; r < 5; ++r) {
            float2 kv = __half22float2(kraw[k][r]);
            float mkv = __half2float(mraw[k][r]);
            x[k][r] = mkf2(kv.x, kv.y) * mkv;   // one v_pk_mul_f32
        }
    }
    fft320xK<4>(t, x);
    #pragma unroll
    for (int k = 0; k < 4; ++k) {
        const int mm = wave + 4 * k;
        #pragma unroll
        for (int s5 = 0; s5 < 5; ++s5) {
            int v = t.J + 64 * s5;
            tile[v * 17 + mm] = __floats2half2_rn(x[k][s5].x, x[k][s5].y);
        }
    }
    __syncthreads();
    __half2* dst = Z + (size_t)q * NPIX + m0;
    for (int j = threadIdx.x; j < NXY * 16; j += blockDim.x) {
        int mm = j & 15, v = j >> 4;
        dst[(size_t)v * NXY + mm] = tile[v * 17 + mm];
    }
}

// Column FFTs (over m) + coil combine; K=2 ILP, coils split across blockIdx.z.
// Software-pipelined coil loop: Z for coil c+1 prefetches under coil c's FFT;
// smaps for c+1 prefetch under iteration c+1's convert+FFT.
__global__ __launch_bounds__(256) void k_fft_cols_combine(const __half2* __restrict__ Z,
                                                          const __half2* __restrict__ smapsP,
                                                          __half2* __restrict__ imtP,
                                                          int t0, int G) {
    const int vtile = blockIdx.x;   // 0..39
    const int tc = blockIdx.y;
    const int half = blockIdx.z;    // 0/1 -> coils [10h, 10h+10)
    const int wave = threadIdx.x >> 6;
    const int lane = threadIdx.x & 63;
    const int v0 = vtile * 8;
    const int vA = v0 + wave;       // vB = vA + 4 (constant offset from colA/spA)
    __shared__ __half2 tile[NXY * 9];   // [u][8 v + 1 pad]
    const int c0 = half * 10;
    const size_t zStride = (size_t)G * NPIX;          // half2 per coil in Z
    const size_t sStride = (size_t)NXY * 5 * 64;      // half2 per coil in smapsP
    const __half2* colA = Z + (size_t)(c0 * G + tc) * NPIX + (size_t)vA * NXY + lane * 5;
    const __half2* spA = smapsP + (size_t)((c0 * NXY + vA) * 5) * 64 + lane;

    // Prologue prefetch (coil c0): Z columns + smaps, raw half2 registers.
    __half2 pf[2][5], sm[2][5];
    #pragma unroll
    for (int r = 0; r < 5; ++r) {
        pf[0][r] = colA[r];
        pf[1][r] = colA[4 * NXY + r];
    }
    #pragma unroll
    for (int s5 = 0; s5 < 5; ++s5) {
        sm[0][s5] = spA[s5 * 64];
        sm[1][s5] = spA[s5 * 64 + 4 * 5 * 64];
    }
    Tw t;
    tw_init(t);   // overlaps prologue loads
    f2 acc[2][5];
    #pragma unroll
    for (int k = 0; k < 2; ++k)
        #pragma unroll
        for (int s5 = 0; s5 < 5; ++s5) acc[k][s5] = mkf2(0.f, 0.f);

    for (int ci = 0; ci < 10; ++ci) {
        // consume prefetched Z
        f2 x[2][5];
        #pragma unroll
        for (int r = 0; r < 5; ++r) {
            float2 a = __half22float2(pf[0][r]);
            float2 b = __half22float2(pf[1][r]);
            x[0][r] = mkf2(a.x, a.y);
            x[1][r] = mkf2(b.x, b.y);
        }
        // issue next coil's Z loads — hidden under the FFT below
        if (ci < 9) {
            colA += zStride;
            #pragma unroll
            for (int r = 0; r < 5; ++r) {
                pf[0][r] = colA[r];
                pf[1][r] = colA[4 * NXY + r];
            }
        }
        fft320xK<2>(t, x);
        // combine with (prefetched) smaps for this coil:
        // acc += out * (sx,sx) + out.yx * (-sy, sy)   -> 2 pk_fma each
        #pragma unroll
        for (int s5 = 0; s5 < 5; ++s5) {
            float2 sA = __half22float2(sm[0][s5]);
            float2 sB = __half22float2(sm[1][s5]);
            acc[0][s5] += x[0][s5] * mkf2(sA.x, sA.x);
            acc[0][s5] += x[0][s5].yx * mkf2(-sA.y, sA.y);
            acc[1][s5] += x[1][s5] * mkf2(sB.x, sB.x);
            acc[1][s5] += x[1][s5].yx * mkf2(-sB.y, sB.y);
        }
        // issue next coil's smaps loads — hidden under next iter's convert+FFT
        if (ci < 9) {
            spA += sStride;
            #pragma unroll
            for (int s5 = 0; s5 < 5; ++s5) {
                sm[0][s5] = spA[s5 * 64];
                sm[1][s5] = spA[s5 * 64 + 4 * 5 * 64];
            }
        }
    }
    #pragma unroll
    for (int s5 = 0; s5 < 5; ++s5) {
        int u = t.J + 64 * s5;
        tile[u * 9 + wave] = __floats2half2_rn(acc[0][s5].x, acc[0][s5].y);
        tile[u * 9 + 4 + wave] = __floats2half2_rn(acc[1][s5].x, acc[1][s5].y);
    }
    __syncthreads();
    __half2* dst = imtP + (size_t)(half * NT + t0 + tc) * NPIX + v0;
    for (int j = threadIdx.x; j < NXY * 8; j += blockDim.x) {
        int vv = j & 7, u = j >> 3;
        dst[(size_t)u * NXY + vv] = tile[u * 9 + vv];
    }
}

// Bilinear warp + sum over t; reduces the two coil-half partials.
__global__ __launch_bounds__(256) void k_warp_sum(const __half2* __restrict__ imtP,
                                                  const float* __restrict__ flow,
                                                  float* __restrict__ out) {
    const int p0 = blockIdx.x * 256;
    const int tid = threadIdx.x;
    __shared__ float s_fl[2 * NT * 257];
    for (int j = tid; j < 256 * 50; j += 256) {
        int pp = j / 50, rem = j - pp * 50;
        int d = rem / 25, tt = rem - d * 25;
        s_fl[(d * NT + tt) * 257 + pp] = flow[(size_t)p0 * 50 + j];
    }
    __syncthreads();
    const int p = p0 + tid;
    const int x = p / NXY, y = p - x * NXY;
    const float fx = (float)x, fy = (float)y;
    float ar = 0.f, ai = 0.f;
    for (int t = 0; t < NT; ++t) {
        float u = s_fl[t * 257 + tid];
        float v = s_fl[(NT + t) * 257 + tid];
        float xs = fminf(fmaxf(fx + u, 0.0f), 319.0f);
        float ys = fminf(fmaxf(fy + v, 0.0f), 319.0f);
        float x0f = floorf(xs), y0f = floorf(ys);
        int x0 = (int)x0f, y0 = (int)y0f;
        int x1 = min(x0 + 1, NXY - 1), y1 = min(y0 + 1, NXY - 1);
        float wx = xs - x0f, wy = ys - y0f;
        const __half2* b0 = imtP + (size_t)t * NPIX;
        const __half2* b1 = imtP + (size_t)(NT + t) * NPIX;
        int i00 = x0 * NXY + y0, i01 = x0 * NXY + y1;
        int i10 = x1 * NXY + y0, i11 = x1 * NXY + y1;
        float2 c00 = __half22float2(b0[i00]); float2 d00 = __half22float2(b1[i00]);
        float2 c01 = __half22float2(b0[i01]); float2 d01 = __half22float2(b1[i01]);
        float2 c10 = __half22float2(b0[i10]); float2 d10 = __half22float2(b1[i10]);
        float2 c11 = __half22float2(b0[i11]); float2 d11 = __half22float2(b1[i11]);
        c00.x += d00.x; c00.y += d00.y;
        c01.x += d01.x; c01.y += d01.y;
        c10.x += d10.x; c10.y += d10.y;
        c11.x += d11.x; c11.y += d11.y;
        float w00 = (1.f - wx) * (1.f - wy), w01 = (1.f - wx) * wy;
        float w10 = wx * (1.f - wy), w11 = wx * wy;
        ar += c00.x * w00 + c01.x * w01 + c10.x * w10 + c11.x * w11;
        ai += c00.y * w00 + c01.y * w01 + c10.y * w10 + c11.y * w11;
    }
    out[p] = ar;
    out[NPIX + p] = ai;
}

extern "C" void kernel_launch(void* const* d_in, const int* in_sizes, int n_in,
                              void* d_out, int out_size, void* d_ws, size_t ws_size,
                              hipStream_t stream) {
    const float* ksr = (const float*)d_in[0];
    const float* ksi = (const float*)d_in[1];
    const float* mask = (const float*)d_in[2];
    const float* smr = (const float*)d_in[3];
    const float* smi = (const float*)d_in[4];
    const float* flow = (const float*)d_in[5];
    float* out = (float*)d_out;

    char* ws = (char*)d_ws;
    const size_t smapsC_bytes = (size_t)NC * NPIX * sizeof(float2);          // 16.4 MB
    const size_t smapsP_bytes = (size_t)NC * NPIX * sizeof(__half2);         // 8.2 MB
    const size_t ksS_bytes = (size_t)NC * NPIX * sizeof(__half2);            // 8.2 MB
    const size_t imtP_bytes = (size_t)2 * NT * NPIX * sizeof(__half2);       // 20.5 MB
    const size_t fixed = smapsC_bytes + smapsP_bytes + ksS_bytes + imtP_bytes;
    // per-t: Z (half2) + maskT (half)
    const size_t per_t = (size_t)NC * NPIX * (sizeof(__half2) + sizeof(__half)); // 12.3 MB

    int G = 1;
    if (ws_size > fixed + per_t) {
        size_t g = (ws_size - fixed) / per_t;
        G = (int)(g > (size_t)NT ? (size_t)NT : g);
    }
    if (G < 1) G = 1;

    float2* smapsC = (float2*)ws;
    __half2* smapsP = (__half2*)(ws + smapsC_bytes);
    __half2* ksS = (__half2*)(ws + smapsC_bytes + smapsP_bytes);
    __half2* imtP = (__half2*)(ws + smapsC_bytes + smapsP_bytes + ksS_bytes);
    __half2* Z = (__half2*)(ws + fixed);
    __half* maskT = (__half*)(ws + fixed + (size_t)NC * G * NPIX * sizeof(__half2));

    k_prep_smaps<<<NPIX / 64, 256, 0, stream>>>(smr, smi, smapsC);
    k_perm_smaps<<<dim3(NC, 5, 5), 256, 0, stream>>>(smapsC, smapsP);
    k_prep_ks<<<NPIX / 64, 256, 0, stream>>>(ksr, ksi, ksS);
    for (int t0 = 0; t0 < NT; t0 += G) {
        int g = (NT - t0) < G ? (NT - t0) : G;
        k_transpose_mask<<<dim3(NPIX / 64, NC), 256, 0, stream>>>(mask, maskT, t0, g);
        k_fft_rows<<<dim3(NC * g, 20), 256, 0, stream>>>(maskT, ksS, Z, g);
        k_fft_cols_combine<<<dim3(40, g, 2), 256, 0, stream>>>(Z, smapsP, imtP, t0, g);
    }
    k_warp_sum<<<NPIX / 256, 256, 0, stream>>>(imtP, flow, out);
}

// Round 6
// 634.685 us; speedup vs baseline: 1.0676x; 1.0471x over previous
//
#include <hip/hip_runtime.h>
#include <hip/hip_fp16.h>
#include <math.h>

#define NXY 320
#define NC 20
#define NT 25
#define NPIX 102400   // 320*320
#define PI_F 3.14159265358979f
#define TWOPI_F 6.28318530717959f

// Packed 2xf32 — lowers to v_pk_fma_f32 / v_pk_mul_f32 / v_pk_add_f32 on gfx950.
typedef float f2 __attribute__((ext_vector_type(2)));
typedef unsigned uint2e __attribute__((ext_vector_type(2)));

__device__ __forceinline__ f2 mkf2(float a, float b) { f2 r; r.x = a; r.y = b; return r; }

// gfx950 VALU-pipe lane swaps for the h=32 / h=16 butterfly stages.
#if defined(__has_builtin)
#if __has_builtin(__builtin_amdgcn_permlane32_swap) && __has_builtin(__builtin_amdgcn_permlane16_swap)
#define USE_PERMLANE_SWAP 1
#endif
#endif
#ifndef USE_PERMLANE_SWAP
#define USE_PERMLANE_SWAP 0
#endif

// Per-lane FFT twiddles, pre-packed for pk-f32 complex multiply:
//   res = d * stxx + d.yx * stym   computes (d.x*c - d.y*s, d.x*s + d.y*c)
struct Tw {
    f2 stxx[6];   // (c, c)
    f2 stym[6];   // (-s, s)
    float sgn[6]; // +1 lower, -1 upper
    f2 w5xx[5];   // (c, c) of e^{+2*pi*i * r*J / 320}
    f2 w5ym[5];   // (-s, s)
    int J;        // bitrev6(lane)
};

__device__ __forceinline__ void tw_init(Tw& t) {
    const int lane = threadIdx.x & 63;
    #pragma unroll
    for (int s = 0; s < 6; ++s) {
        const int h = 32 >> s;
        const bool up = (lane & h) != 0;
        t.sgn[s] = up ? -1.0f : 1.0f;
        float cc = 1.0f, ss = 0.0f;
        if (up) __sincosf(PI_F * (float)(lane & (h - 1)) / (float)h, &ss, &cc);
        t.stxx[s] = mkf2(cc, cc);
        t.stym[s] = mkf2(-ss, ss);
    }
    t.J = (int)(__brev((unsigned)lane) >> 26);
    t.w5xx[0] = mkf2(1.0f, 1.0f);
    t.w5ym[0] = mkf2(0.0f, 0.0f);
    #pragma unroll
    for (int r = 1; r < 5; ++r) {
        float ss, cc;
        __sincosf(TWOPI_F * (float)(r * t.J) / 320.0f, &ss, &cc);
        t.w5xx[r] = mkf2(cc, cc);
        t.w5ym[r] = mkf2(-ss, ss);
    }
}

// K interleaved 320-point DFTs (+i sign) by one wave. IN-PLACE: result in x.
// All complex arithmetic on f2 vectors -> packed v_pk_* f32 ops (2x issue width).
template <int K>
__device__ __forceinline__ void fft320xK(const Tw& t, f2 (&x)[K][5]) {
#if USE_PERMLANE_SWAP
    #pragma unroll
    for (int s = 0; s < 2; ++s) {
        #pragma unroll
        for (int r = 0; r < 5; ++r) {
            #pragma unroll
            for (int k = 0; k < K; ++k) {
                uint2e px, py;
                if (s == 0) {
                    px = __builtin_amdgcn_permlane32_swap(
                        __float_as_uint(x[k][r].x), __float_as_uint(x[k][r].x), false, false);
                    py = __builtin_amdgcn_permlane32_swap(
                        __float_as_uint(x[k][r].y), __float_as_uint(x[k][r].y), false, false);
                } else {
                    px = __builtin_amdgcn_permlane16_swap(
                        __float_as_uint(x[k][r].x), __float_as_uint(x[k][r].x), false, false);
                    py = __builtin_amdgcn_permlane16_swap(
                        __float_as_uint(x[k][r].y), __float_as_uint(x[k][r].y), false, false);
                }
                // px[0] = value at (lane & ~h) [lo], px[1] = value at (lane | h) [hi]
                f2 lo = mkf2(__uint_as_float(px[0]), __uint_as_float(py[0]));
                f2 hi = mkf2(__uint_as_float(px[1]), __uint_as_float(py[1]));
                f2 d = lo + hi * t.sgn[s];
                x[k][r] = d * t.stxx[s] + d.yx * t.stym[s];
            }
        }
    }
    constexpr int S0 = 2;
#else
    constexpr int S0 = 0;
#endif
    #pragma unroll
    for (int s = S0; s < 6; ++s) {
        const int h = 32 >> s;
        #pragma unroll
        for (int r = 0; r < 5; ++r) {
            #pragma unroll
            for (int k = 0; k < K; ++k) {
                f2 o = mkf2(__shfl_xor(x[k][r].x, h), __shfl_xor(x[k][r].y, h));
                f2 d = o + x[k][r] * t.sgn[s];
                x[k][r] = d * t.stxx[s] + d.yx * t.stym[s];
            }
        }
    }
    const float W5x[5] = {1.0f, 0.309016994f, -0.809016994f, -0.809016994f, 0.309016994f};
    const float W5y[5] = {0.0f, 0.951056516f, 0.587785252f, -0.587785252f, -0.951056516f};
    #pragma unroll
    for (int k = 0; k < K; ++k) {
        f2 T[5];
        T[0] = x[k][0];
        #pragma unroll
        for (int r = 1; r < 5; ++r) {
            f2 a = x[k][r];
            T[r] = a * t.w5xx[r] + a.yx * t.w5ym[r];
        }
        #pragma unroll
        for (int s5 = 0; s5 < 5; ++s5) {
            f2 acc = T[0];
            #pragma unroll
            for (int r = 1; r < 5; ++r) {
                const int kk = (r * s5) % 5;
                acc += T[r] * W5x[kk];
                acc += T[r].yx * mkf2(-W5y[kk], W5y[kk]);
            }
            x[k][s5] = acc;
        }
    }
}

// smapsC[c][p] = conj(smaps[p][c]) * (-1)^(m+n) / 320   (fp32 staging table)
__global__ __launch_bounds__(256) void k_prep_smaps(const float* __restrict__ smr,
                                                    const float* __restrict__ smi,
                                                    float2* __restrict__ smapsC) {
    const int p0 = blockIdx.x * 64;
    __shared__ float s_r[64 * 21];
    __shared__ float s_i[64 * 21];
    for (int j = threadIdx.x; j < 64 * NC; j += blockDim.x) {
        int p = j / NC, c = j - p * NC;
        s_r[p * 21 + c] = smr[(size_t)p0 * NC + j];
        s_i[p * 21 + c] = smi[(size_t)p0 * NC + j];
    }
    __syncthreads();
    for (int j = threadIdx.x; j < 64 * NC; j += blockDim.x) {
        int c = j >> 6, p = j & 63;
        int pg = p0 + p;
        int m = pg / NXY, n = pg - m * NXY;
        float sgn = (((m + n) & 1) ? -1.0f : 1.0f) * (1.0f / 320.0f);
        smapsC[(size_t)c * NPIX + pg] = make_float2(s_r[p * 21 + c] * sgn,
                                                    -s_i[p * 21 + c] * sgn);
    }
}

// smapsP[((c*320 + v)*5 + s5)*64 + lane] = smapsC[c][(bitrev6(lane)+64*s5)*320 + v] (half2)
__global__ __launch_bounds__(256) void k_perm_smaps(const float2* __restrict__ smapsC,
                                                    __half2* __restrict__ smapsP) {
    const int c = blockIdx.x;
    const int s5 = blockIdx.y;
    const int v0 = blockIdx.z * 64;
    __shared__ __half2 t2[64 * 65];
    for (int j = threadIdx.x; j < 64 * 64; j += blockDim.x) {
        int ur = j >> 6, vc = j & 63;
        float2 v = smapsC[(size_t)c * NPIX + (size_t)(s5 * 64 + ur) * NXY + v0 + vc];
        t2[ur * 65 + vc] = __floats2half2_rn(v.x, v.y);
    }
    __syncthreads();
    for (int j = threadIdx.x; j < 64 * 64; j += blockDim.x) {
        int vr = j >> 6, lane = j & 63;
        int J = (int)(__brev((unsigned)lane) >> 26);
        smapsP[(size_t)((c * NXY + v0 + vr) * 5 + s5) * 64 + lane] = t2[J * 65 + vr];
    }
}

// ksS[c][p] = (ksr + i*ksi)(p,c) * (-1)^(m+n)   (half2, pre-mask)
__global__ __launch_bounds__(256) void k_prep_ks(const float* __restrict__ ksr,
                                                 const float* __restrict__ ksi,
                                                 __half2* __restrict__ ksS) {
    const int p0 = blockIdx.x * 64;
    __shared__ float s_r[64 * 21];
    __shared__ float s_i[64 * 21];
    for (int j = threadIdx.x; j < 64 * NC; j += blockDim.x) {
        int p = j / NC, c = j - p * NC;
        s_r[p * 21 + c] = ksr[(size_t)p0 * NC + j];
        s_i[p * 21 + c] = ksi[(size_t)p0 * NC + j];
    }
    __syncthreads();
    for (int j = threadIdx.x; j < 64 * NC; j += blockDim.x) {
        int c = j >> 6, p = j & 63;
        int pg = p0 + p;
        int m = pg / NXY, n = pg - m * NXY;
        float sgn = ((m + n) & 1) ? -1.0f : 1.0f;
        ksS[(size_t)c * NPIX + pg] =
            __floats2half2_rn(s_r[p * 21 + c] * sgn, s_i[p * 21 + c] * sgn);
    }
}

// Dense transpose: maskT[(c*G+tc)][p] = (half)mask[p][c*25 + t0 + tc].
__global__ __launch_bounds__(256) void k_transpose_mask(const float* __restrict__ mask,
                                                        __half* __restrict__ maskT,
                                                        int t0, int G) {
    const int p0 = blockIdx.x * 64;
    const int c = blockIdx.y;
    __shared__ float tile[64 * 26];
    if (G == NT) {
        for (int j = threadIdx.x; j < 64 * NT; j += 256) {
            int pl = j / NT, tc = j - pl * NT;  // compile-time divisor
            tile[pl * 26 + tc] = mask[(size_t)(p0 + pl) * (NC * NT) + c * NT + tc];
        }
    } else {
        for (int j = threadIdx.x; j < 64 * G; j += 256) {
            int pl = j / G, tc = j - pl * G;
            tile[pl * 26 + tc] = mask[(size_t)(p0 + pl) * (NC * NT) + c * NT + t0 + tc];
        }
    }
    __syncthreads();
    for (int j = threadIdx.x; j < 16 * G; j += 256) {
        int p4 = (j & 15) * 4, tc = j >> 4;
        union { __half2 h2[2]; uint2 u; } pk;
        pk.h2[0] = __floats2half2_rn(tile[(p4 + 0) * 26 + tc], tile[(p4 + 1) * 26 + tc]);
        pk.h2[1] = __floats2half2_rn(tile[(p4 + 2) * 26 + tc], tile[(p4 + 3) * 26 + tc]);
        *reinterpret_cast<uint2*>(maskT + (size_t)(c * G + tc) * NPIX + p0 + p4) = pk.u;
    }
}

// FUSED: maskT*kspace + row FFTs (over n). One block = 16 rows of one (c,tc).
// TILED Z OUTPUT: Z[q][(mtile*320 + v)*16 + mm] — block writes one contiguous
// 20 KB span with uint4 stores (was 64-B runs at 1280-B stride -> 2x HBM
// write amplification, WRITE_SIZE 250 MB vs 131 MB ideal at G=16).
__global__ __launch_bounds__(256) void k_fft_rows(const __half* __restrict__ maskT,
                                                  const __half2* __restrict__ ksS,
                                                  __half2* __restrict__ Z,
                                                  int G) {
    const int q = blockIdx.x;       // c*G + tc
    const int mtile = blockIdx.y;   // 0..19
    const int c = q / G;            // once per block (scalar)
    const int wave = threadIdx.x >> 6;
    const int lane = threadIdx.x & 63;
    const int m0 = mtile * 16;
    __shared__ __half2 tile[NXY * 17];  // [v][16 + 1 pad]
    const __half2* ks_c = ksS + (size_t)c * NPIX;
    const __half* mk_q = maskT + (size_t)q * NPIX;
    __half2 kraw[4][5];
    __half  mraw[4][5];
    #pragma unroll
    for (int k = 0; k < 4; ++k) {
        const int pbase = (m0 + wave + 4 * k) * NXY + lane * 5;
        const __half2* kp = ks_c + pbase;
        const __half* mp = mk_q + pbase;
        #pragma unroll
        for (int r = 0; r < 5; ++r) { kraw[k][r] = kp[r]; mraw[k][r] = mp[r]; }
    }
    Tw t;
    tw_init(t);   // TRANS-pipe work overlaps the loads above
    f2 x[4][5];
    #pragma unroll
    for (int k = 0; k < 4; ++k) {
        #pragma unroll
        for (int r = 0; r < 5; ++r) {
            float2 kv = __half22float2(kraw[k][r]);
            float mkv = __half2float(mraw[k][r]);
            x[k][r] = mkf2(kv.x, kv.y) * mkv;   // one v_pk_mul_f32
        }
    }
    fft320xK<4>(t, x);
    #pragma unroll
    for (int k = 0; k < 4; ++k) {
        const int mm = wave + 4 * k;
        #pragma unroll
        for (int s5 = 0; s5 < 5; ++s5) {
            int v = t.J + 64 * s5;
            tile[v * 17 + mm] = __floats2half2_rn(x[k][s5].x, x[k][s5].y);
        }
    }
    __syncthreads();
    // contiguous tiled writeback: element (v,mm) -> dstt[v*16+mm]
    __half2* dstt = Z + ((size_t)(q * 20 + mtile) * NXY) * 16;
    for (int j = threadIdx.x; j < NXY * 4; j += blockDim.x) {   // 1280 x 16B
        int v = j >> 2, h = (j & 3) * 4;
        union { __half2 h2[4]; uint4 u4; } pk;
        #pragma unroll
        for (int e = 0; e < 4; ++e) pk.h2[e] = tile[v * 17 + h + e];
        *reinterpret_cast<uint4*>(dstt + (size_t)v * 16 + h) = pk.u4;
    }
}

// Column FFTs (over m) + coil combine; K=2 ILP, coils split across blockIdx.z.
// Reads TILED Z: 5 per-lane offsets precomputed once; coil loop body unchanged.
__global__ __launch_bounds__(256) void k_fft_cols_combine(const __half2* __restrict__ Z,
                                                          const __half2* __restrict__ smapsP,
                                                          __half2* __restrict__ imtP,
                                                          int t0, int G) {
    const int vtile = blockIdx.x;   // 0..39
    const int tc = blockIdx.y;
    const int half = blockIdx.z;    // 0/1 -> coils [10h, 10h+10)
    const int wave = threadIdx.x >> 6;
    const int lane = threadIdx.x & 63;
    const int v0 = vtile * 8;
    const int vA = v0 + wave;       // vB = vA + 4
    __shared__ __half2 tile[NXY * 9];   // [u][8 v + 1 pad]
    const int c0 = half * 10;
    const size_t zStride = (size_t)G * NPIX;          // half2 per coil in Z
    const size_t sStride = (size_t)NXY * 5 * 64;      // half2 per coil in smapsP
    // tiled-Z offsets for m = lane*5 + r at column vA (vB = +64 half2)
    int off5[5];
    #pragma unroll
    for (int r = 0; r < 5; ++r) {
        int m = lane * 5 + r;
        off5[r] = ((m >> 4) * NXY + vA) * 16 + (m & 15);
    }
    const __half2* zq = Z + (size_t)(c0 * G + tc) * NPIX;
    const __half2* spA = smapsP + (size_t)((c0 * NXY + vA) * 5) * 64 + lane;

    // Prologue prefetch (coil c0): Z columns + smaps, raw half2 registers.
    __half2 pf[2][5], sm[2][5];
    #pragma unroll
    for (int r = 0; r < 5; ++r) {
        pf[0][r] = zq[off5[r]];
        pf[1][r] = zq[off5[r] + 64];
    }
    #pragma unroll
    for (int s5 = 0; s5 < 5; ++s5) {
        sm[0][s5] = spA[s5 * 64];
        sm[1][s5] = spA[s5 * 64 + 4 * 5 * 64];
    }
    Tw t;
    tw_init(t);   // overlaps prologue loads
    f2 acc[2][5];
    #pragma unroll
    for (int k = 0; k < 2; ++k)
        #pragma unroll
        for (int s5 = 0; s5 < 5; ++s5) acc[k][s5] = mkf2(0.f, 0.f);

    for (int ci = 0; ci < 10; ++ci) {
        // consume prefetched Z
        f2 x[2][5];
        #pragma unroll
        for (int r = 0; r < 5; ++r) {
            float2 a = __half22float2(pf[0][r]);
            float2 b = __half22float2(pf[1][r]);
            x[0][r] = mkf2(a.x, a.y);
            x[1][r] = mkf2(b.x, b.y);
        }
        // issue next coil's Z loads — hidden under the FFT below
        if (ci < 9) {
            zq += zStride;
            #pragma unroll
            for (int r = 0; r < 5; ++r) {
                pf[0][r] = zq[off5[r]];
                pf[1][r] = zq[off5[r] + 64];
            }
        }
        fft320xK<2>(t, x);
        // combine with (prefetched) smaps for this coil:
        // acc += out * (sx,sx) + out.yx * (-sy, sy)   -> 2 pk_fma each
        #pragma unroll
        for (int s5 = 0; s5 < 5; ++s5) {
            float2 sA = __half22float2(sm[0][s5]);
            float2 sB = __half22float2(sm[1][s5]);
            acc[0][s5] += x[0][s5] * mkf2(sA.x, sA.x);
            acc[0][s5] += x[0][s5].yx * mkf2(-sA.y, sA.y);
            acc[1][s5] += x[1][s5] * mkf2(sB.x, sB.x);
            acc[1][s5] += x[1][s5].yx * mkf2(-sB.y, sB.y);
        }
        // issue next coil's smaps loads — hidden under next iter's convert+FFT
        if (ci < 9) {
            spA += sStride;
            #pragma unroll
            for (int s5 = 0; s5 < 5; ++s5) {
                sm[0][s5] = spA[s5 * 64];
                sm[1][s5] = spA[s5 * 64 + 4 * 5 * 64];
            }
        }
    }
    #pragma unroll
    for (int s5 = 0; s5 < 5; ++s5) {
        int u = t.J + 64 * s5;
        tile[u * 9 + wave] = __floats2half2_rn(acc[0][s5].x, acc[0][s5].y);
        tile[u * 9 + 4 + wave] = __floats2half2_rn(acc[1][s5].x, acc[1][s5].y);
    }
    __syncthreads();
    __half2* dst = imtP + (size_t)(half * NT + t0 + tc) * NPIX + v0;
    for (int j = threadIdx.x; j < NXY * 8; j += blockDim.x) {
        int vv = j & 7, u = j >> 3;
        dst[(size_t)u * NXY + vv] = tile[u * 9 + vv];
    }
}

// Bilinear warp + sum over t; reduces the two coil-half partials.
__global__ __launch_bounds__(256) void k_warp_sum(const __half2* __restrict__ imtP,
                                                  const float* __restrict__ flow,
                                                  float* __restrict__ out) {
    const int p0 = blockIdx.x * 256;
    const int tid = threadIdx.x;
    __shared__ float s_fl[2 * NT * 257];
    for (int j = tid; j < 256 * 50; j += 256) {
        int pp = j / 50, rem = j - pp * 50;
        int d = rem / 25, tt = rem - d * 25;
        s_fl[(d * NT + tt) * 257 + pp] = flow[(size_t)p0 * 50 + j];
    }
    __syncthreads();
    const int p = p0 + tid;
    const int x = p / NXY, y = p - x * NXY;
    const float fx = (float)x, fy = (float)y;
    float ar = 0.f, ai = 0.f;
    for (int t = 0; t < NT; ++t) {
        float u = s_fl[t * 257 + tid];
        float v = s_fl[(NT + t) * 257 + tid];
        float xs = fminf(fmaxf(fx + u, 0.0f), 319.0f);
        float ys = fminf(fmaxf(fy + v, 0.0f), 319.0f);
        float x0f = floorf(xs), y0f = floorf(ys);
        int x0 = (int)x0f, y0 = (int)y0f;
        int x1 = min(x0 + 1, NXY - 1), y1 = min(y0 + 1, NXY - 1);
        float wx = xs - x0f, wy = ys - y0f;
        const __half2* b0 = imtP + (size_t)t * NPIX;
        const __half2* b1 = imtP + (size_t)(NT + t) * NPIX;
        int i00 = x0 * NXY + y0, i01 = x0 * NXY + y1;
        int i10 = x1 * NXY + y0, i11 = x1 * NXY + y1;
        float2 c00 = __half22float2(b0[i00]); float2 d00 = __half22float2(b1[i00]);
        float2 c01 = __half22float2(b0[i01]); float2 d01 = __half22float2(b1[i01]);
        float2 c10 = __half22float2(b0[i10]); float2 d10 = __half22float2(b1[i10]);
        float2 c11 = __half22float2(b0[i11]); float2 d11 = __half22float2(b1[i11]);
        c00.x += d00.x; c00.y += d00.y;
        c01.x += d01.x; c01.y += d01.y;
        c10.x += d10.x; c10.y += d10.y;
        c11.x += d11.x; c11.y += d11.y;
        float w00 = (1.f - wx) * (1.f - wy), w01 = (1.f - wx) * wy;
        float w10 = wx * (1.f - wy), w11 = wx * wy;
        ar += c00.x * w00 + c01.x * w01 + c10.x * w10 + c11.x * w11;
        ai += c00.y * w00 + c01.y * w01 + c10.y * w10 + c11.y * w11;
    }
    out[p] = ar;
    out[NPIX + p] = ai;
}

extern "C" void kernel_launch(void* const* d_in, const int* in_sizes, int n_in,
                              void* d_out, int out_size, void* d_ws, size_t ws_size,
                              hipStream_t stream) {
    const float* ksr = (const float*)d_in[0];
    const float* ksi = (const float*)d_in[1];
    const float* mask = (const float*)d_in[2];
    const float* smr = (const float*)d_in[3];
    const float* smi = (const float*)d_in[4];
    const float* flow = (const float*)d_in[5];
    float* out = (float*)d_out;

    char* ws = (char*)d_ws;
    const size_t smapsC_bytes = (size_t)NC * NPIX * sizeof(float2);          // 16.4 MB
    const size_t smapsP_bytes = (size_t)NC * NPIX * sizeof(__half2);         // 8.2 MB
    const size_t ksS_bytes = (size_t)NC * NPIX * sizeof(__half2);            // 8.2 MB
    const size_t imtP_bytes = (size_t)2 * NT * NPIX * sizeof(__half2);       // 20.5 MB
    const size_t fixed = smapsC_bytes + smapsP_bytes + ksS_bytes + imtP_bytes;
    // per-t: Z (half2) + maskT (half)
    const size_t per_t = (size_t)NC * NPIX * (sizeof(__half2) + sizeof(__half)); // 12.3 MB

    int G = 1;
    if (ws_size > fixed + per_t) {
        size_t g = (ws_size - fixed) / per_t;
        G = (int)(g > (size_t)NT ? (size_t)NT : g);
    }
    if (G < 1) G = 1;
    // balance chunks: e.g. G=16 -> 13+12 instead of 16+9 (keeps tail launches fed)
    {
        int R = (NT + G - 1) / G;
        G = (NT + R - 1) / R;
    }

    float2* smapsC = (float2*)ws;
    __half2* smapsP = (__half2*)(ws + smapsC_bytes);
    __half2* ksS = (__half2*)(ws + smapsC_bytes + smapsP_bytes);
    __half2* imtP = (__half2*)(ws + smapsC_bytes + smapsP_bytes + ksS_bytes);
    __half2* Z = (__half2*)(ws + fixed);
    __half* maskT = (__half*)(ws + fixed + (size_t)NC * G * NPIX * sizeof(__half2));

    k_prep_smaps<<<NPIX / 64, 256, 0, stream>>>(smr, smi, smapsC);
    k_perm_smaps<<<dim3(NC, 5, 5), 256, 0, stream>>>(smapsC, smapsP);
    k_prep_ks<<<NPIX / 64, 256, 0, stream>>>(ksr, ksi, ksS);
    for (int t0 = 0; t0 < NT; t0 += G) {
        int g = (NT - t0) < G ? (NT - t0) : G;
        k_transpose_mask<<<dim3(NPIX / 64, NC), 256, 0, stream>>>(mask, maskT, t0, g);
        k_fft_rows<<<dim3(NC * g, 20), 256, 0, stream>>>(maskT, ksS, Z, g);
        k_fft_cols_combine<<<dim3(40, g, 2), 256, 0, stream>>>(Z, smapsP, imtP, t0, g);
    }
    k_warp_sum<<<NPIX / 256, 256, 0, stream>>>(imtP, flow, out);
}